// Round 2
// baseline (328.851 us; speedup 1.0000x reference)
//
#include <hip/hip_runtime.h>
#include <math.h>

#define B_ROWS 65536
#define N_COLS 512
#define EPS 1e-8f
#define GRID1 2048   // 2048 blocks x 4 waves x 8 rows = 65536 rows

// ws layout (floats):
//   [0, 65536)          sim
//   [65536, +128*512)   colsum per residue s=row&127 (256 KB)
//   [.., +512)          colTot[j] = sum_s colsum_s[j]
//   [.., +16)           acc[0]=sum max(log sim,-100), acc[1]=sum max(sim,eps),
//                       acc[2]=sum_s <colsum_s, simslab_s>  (toe total)
//
// Algebraic eliminations (sim<1 and toe<1 strictly, so max(log(.),EPS)==EPS):
//   second = EPS * sum(sim); third = EPS/N * sum_s <colsum_s, simslab_s>.
// Removes the entire second pass over A/P.
//
// This revision vs. 297us version:
//  - k_main: 1-row pipeline w/ 1-row prefetch (4 float4 in flight, was 16)
//    + __launch_bounds__(256,8) to get under the 64-VGPR occupancy cliff
//    (was VGPR=68 -> 4 waves/SIMD; target 8 waves/SIMD, full 8 blocks/CU).
//  - k_final (single-block, serial 128-iter loop on one CU) split into
//    k_red (64 blocks) + k_fin (tiny).

__global__ __launch_bounds__(256, 8) void k_main(
        const float* __restrict__ A, const float* __restrict__ Bn,
        float* __restrict__ sim, float* __restrict__ colsum,
        float* __restrict__ acc) {
    __shared__ float cs[512];
    __shared__ float sred[16];
    const int t    = threadIdx.x;
    const int lane = t & 63;
    const int w    = t >> 6;
    const int s    = blockIdx.x & 127;               // this block's residue
    const int kb   = (blockIdx.x >> 7) * 32 + w * 8; // row-multiplier base

    cs[t] = 0.f; cs[t + 256] = 0.f;

    float cacc[8];
#pragma unroll
    for (int k = 0; k < 8; ++k) cacc[k] = 0.f;
    float accLog = 0.f, accSim = 0.f;

    // prefetch row 0 (columns lane*4..+3 and 256+lane*4..+3)
    size_t off = (size_t)(s + 128 * kb) * N_COLS + lane * 4;
    float4 a0 = *(const float4*)(A  + off);
    float4 a1 = *(const float4*)(A  + off + 256);
    float4 b0 = *(const float4*)(Bn + off);
    float4 b1 = *(const float4*)(Bn + off + 256);

#pragma unroll 1
    for (int r = 0; r < 8; ++r) {
        // issue next row's loads before touching current row's data
        float4 na0, na1, nb0, nb1;
        if (r < 7) {
            size_t noff = off + (size_t)128 * N_COLS;
            na0 = *(const float4*)(A  + noff);
            na1 = *(const float4*)(A  + noff + 256);
            nb0 = *(const float4*)(Bn + noff);
            nb1 = *(const float4*)(Bn + noff + 256);
        }

        const float av[8] = {a0.x, a0.y, a0.z, a0.w, a1.x, a1.y, a1.z, a1.w};
        const float bv[8] = {b0.x, b0.y, b0.z, b0.w, b1.x, b1.y, b1.z, b1.w};
        float ea[8];
        float sA = 0.f, sB = 0.f, d = 0.f;
#pragma unroll
        for (int k = 0; k < 8; ++k) {
            float e = __expf(av[k]);
            float f = __expf(bv[k]);
            ea[k] = e;
            sA += e; sB += f; d += e * f;
        }
        // 3 independent butterfly chains
#pragma unroll
        for (int m = 32; m >= 1; m >>= 1) {
            sA += __shfl_xor(sA, m, 64);
            sB += __shfl_xor(sB, m, 64);
            d  += __shfl_xor(d,  m, 64);
        }
        float inv_sa = 1.f / sA;
#pragma unroll
        for (int k = 0; k < 8; ++k) cacc[k] += ea[k] * inv_sa;
        if (lane == 0) {
            float sv = d * inv_sa * (1.f / sB);
            sim[s + 128 * (kb + r)] = sv;
            accLog += fmaxf(__logf(sv), -100.f);
            accSim += fmaxf(sv, EPS);
        }
        if (r < 7) { a0 = na0; a1 = na1; b0 = nb0; b1 = nb1; }
        off += (size_t)128 * N_COLS;
    }

    // ---- epilogue: block reduce (all 4 waves share residue s) ----
    if (lane == 0) { sred[w] = accLog; sred[8 + w] = accSim; }
    __syncthreads();
#pragma unroll
    for (int k = 0; k < 4; ++k) atomicAdd(&cs[lane * 4 + k], cacc[k]);
#pragma unroll
    for (int k = 0; k < 4; ++k) atomicAdd(&cs[256 + lane * 4 + k], cacc[4 + k]);
    __syncthreads();

    float* cdst = colsum + (size_t)s * 512;
    atomicAdd(&cdst[t], cs[t]);
    atomicAdd(&cdst[t + 256], cs[t + 256]);
    if (t == 0) atomicAdd(&acc[0], sred[0] + sred[1] + sred[2] + sred[3]);
    if (t == 1) atomicAdd(&acc[1], sred[8] + sred[9] + sred[10] + sred[11]);
}

// 64 blocks x 512 threads: column totals (for entropy) + toe dot-product.
__global__ __launch_bounds__(512) void k_red(
        const float* __restrict__ colsum, const float* __restrict__ sim,
        float* __restrict__ colTot, float* __restrict__ acc) {
    __shared__ float red[8];
    const int t = threadIdx.x, lane = t & 63, w = t >> 6;
    const int s0 = blockIdx.x * 2;
    float tot = 0.f, toe = 0.f;
#pragma unroll
    for (int k = 0; k < 2; ++k) {
        int idx = (s0 + k) * 512 + t;
        float c = colsum[idx];
        tot += c;
        toe += c * sim[idx];
    }
    atomicAdd(&colTot[t], tot);   // 64-way contention per address: fine
#pragma unroll
    for (int m = 32; m >= 1; m >>= 1) toe += __shfl_xor(toe, m, 64);
    if (lane == 0) red[w] = toe;
    __syncthreads();
    if (t == 0) {
        float tt = red[0] + red[1] + red[2] + red[3]
                 + red[4] + red[5] + red[6] + red[7];
        atomicAdd(&acc[2], tt);
    }
}

__global__ __launch_bounds__(512) void k_fin(
        const float* __restrict__ colTot, const float* __restrict__ acc,
        float* __restrict__ out) {
    __shared__ float red[8];
    const int t = threadIdx.x, lane = t & 63, w = t >> 6;
    float p   = fmaxf(colTot[t] * (1.f / B_ROWS), EPS);
    float ent = -p * __logf(p);
#pragma unroll
    for (int m = 32; m >= 1; m >>= 1) ent += __shfl_xor(ent, m, 64);
    if (lane == 0) red[w] = ent;
    __syncthreads();
    if (t == 0) {
        float entropy = red[0] + red[1] + red[2] + red[3]
                      + red[4] + red[5] + red[6] + red[7];
        float consistency = -acc[0] * (1.f / B_ROWS);
        float second      = acc[1] * EPS;
        float third       = acc[2] * EPS * (1.f / N_COLS);
        float third_weight = 0.5f / sqrtf((float)N_COLS);
        float diff_weight  = 0.25f / (float)N_COLS;
        out[0] = consistency - 2.0f * entropy + diff_weight * second
                 - third_weight * third;
        out[1] = consistency;
        out[2] = entropy;
        out[3] = second;
        out[4] = third;
    }
}

extern "C" void kernel_launch(void* const* d_in, const int* in_sizes, int n_in,
                              void* d_out, int out_size, void* d_ws, size_t ws_size,
                              hipStream_t stream) {
    const float* anchors   = (const float*)d_in[0];
    const float* neighbors = (const float*)d_in[1];
    float* out = (float*)d_out;

    float* sim    = (float*)d_ws;            // 65536 f32
    float* colsum = sim + B_ROWS;            // 128*512 f32 (256 KB)
    float* colTot = colsum + 128 * 512;      // 512 f32
    float* acc    = colTot + 512;            // 16 f32

    // zero colsum + colTot + acc (sim is fully overwritten by k_main)
    hipMemsetAsync(colsum, 0, (128 * 512 + 512 + 16) * sizeof(float), stream);

    k_main<<<dim3(GRID1), dim3(256), 0, stream>>>(
        anchors, neighbors, sim, colsum, acc);
    k_red<<<dim3(64), dim3(512), 0, stream>>>(colsum, sim, colTot, acc);
    k_fin<<<dim3(1), dim3(512), 0, stream>>>(colTot, acc, out);
}

// Round 3
// 298.935 us; speedup vs baseline: 1.1001x; 1.1001x over previous
//
#include <hip/hip_runtime.h>
#include <math.h>

#define B_ROWS 65536
#define N_COLS 512
#define EPS 1e-8f
#define GRID1 2048   // 2048 blocks x 4 waves x 8 rows = 65536 rows

// ws layout (floats):
//   [0, 65536)          sim
//   [65536, +128*512)   colsum per residue s=row&127 (256 KB)
//   [.., +512)          colTot[j] = sum_s colsum_s[j]
//   [.., +16)           acc[0]=sum max(log sim,-100), acc[1]=sum max(sim,eps),
//                       acc[2]=sum_s <colsum_s, simslab_s>  (toe total)
//
// Algebraic eliminations (sim<1 and toe<1 strictly, so max(log(.),EPS)==EPS):
//   second = EPS * sum(sim); third = EPS/N * sum_s <colsum_s, simslab_s>.
//
// R2 post-mortem: __launch_bounds__(256,8) + 4x float4 manual prefetch ->
// allocator capped at 32 VGPR and SPILLED (WRITE_SIZE 6.5->182 MB scratch).
// R3: keep the (256,8) occupancy target but drop the manual prefetch; at
// 8 waves/SIMD TLP hides latency, and the live set (~44 regs) fits under
// the 64-VGPR cliff without spilling.

__global__ __launch_bounds__(256, 8) void k_main(
        const float* __restrict__ A, const float* __restrict__ Bn,
        float* __restrict__ sim, float* __restrict__ colsum,
        float* __restrict__ acc) {
    __shared__ float cs[512];
    __shared__ float sred[16];
    const int t    = threadIdx.x;
    const int lane = t & 63;
    const int w    = t >> 6;
    const int s    = blockIdx.x & 127;               // this block's residue
    const int kb   = (blockIdx.x >> 7) * 32 + w * 8; // row-multiplier base

    cs[t] = 0.f; cs[t + 256] = 0.f;

    float cacc[8];
#pragma unroll
    for (int k = 0; k < 8; ++k) cacc[k] = 0.f;
    float accLog = 0.f, accSim = 0.f;

    size_t off = (size_t)(s + 128 * kb) * N_COLS + lane * 4;

#pragma unroll 1
    for (int r = 0; r < 8; ++r) {
        // 4 independent 16B loads (per-row MLP; TLP from 8 waves/SIMD does
        // the cross-row hiding)
        const float4 a0 = *(const float4*)(A  + off);
        const float4 a1 = *(const float4*)(A  + off + 256);
        const float4 b0 = *(const float4*)(Bn + off);
        const float4 b1 = *(const float4*)(Bn + off + 256);

        const float av[8] = {a0.x, a0.y, a0.z, a0.w, a1.x, a1.y, a1.z, a1.w};
        const float bv[8] = {b0.x, b0.y, b0.z, b0.w, b1.x, b1.y, b1.z, b1.w};
        float ea[8];
        float sA = 0.f, sB = 0.f, d = 0.f;
#pragma unroll
        for (int k = 0; k < 8; ++k) {
            float e = __expf(av[k]);
            float f = __expf(bv[k]);
            ea[k] = e;
            sA += e; sB += f; d += e * f;
        }
        // 3 independent butterfly chains
#pragma unroll
        for (int m = 32; m >= 1; m >>= 1) {
            sA += __shfl_xor(sA, m, 64);
            sB += __shfl_xor(sB, m, 64);
            d  += __shfl_xor(d,  m, 64);
        }
        float inv_sa = 1.f / sA;
#pragma unroll
        for (int k = 0; k < 8; ++k) cacc[k] += ea[k] * inv_sa;
        if (lane == 0) {
            float sv = d * inv_sa * (1.f / sB);
            sim[s + 128 * (kb + r)] = sv;
            accLog += fmaxf(__logf(sv), -100.f);
            accSim += fmaxf(sv, EPS);
        }
        off += (size_t)128 * N_COLS;
    }

    // ---- epilogue: block reduce (all 4 waves share residue s) ----
    if (lane == 0) { sred[w] = accLog; sred[8 + w] = accSim; }
    __syncthreads();
#pragma unroll
    for (int k = 0; k < 4; ++k) atomicAdd(&cs[lane * 4 + k], cacc[k]);
#pragma unroll
    for (int k = 0; k < 4; ++k) atomicAdd(&cs[256 + lane * 4 + k], cacc[4 + k]);
    __syncthreads();

    float* cdst = colsum + (size_t)s * 512;
    atomicAdd(&cdst[t], cs[t]);
    atomicAdd(&cdst[t + 256], cs[t + 256]);
    if (t == 0) atomicAdd(&acc[0], sred[0] + sred[1] + sred[2] + sred[3]);
    if (t == 1) atomicAdd(&acc[1], sred[8] + sred[9] + sred[10] + sred[11]);
}

// 64 blocks x 512 threads: column totals (for entropy) + toe dot-product.
__global__ __launch_bounds__(512) void k_red(
        const float* __restrict__ colsum, const float* __restrict__ sim,
        float* __restrict__ colTot, float* __restrict__ acc) {
    __shared__ float red[8];
    const int t = threadIdx.x, lane = t & 63, w = t >> 6;
    const int s0 = blockIdx.x * 2;
    float tot = 0.f, toe = 0.f;
#pragma unroll
    for (int k = 0; k < 2; ++k) {
        int idx = (s0 + k) * 512 + t;
        float c = colsum[idx];
        tot += c;
        toe += c * sim[idx];
    }
    atomicAdd(&colTot[t], tot);   // 64-way contention per address: fine
#pragma unroll
    for (int m = 32; m >= 1; m >>= 1) toe += __shfl_xor(toe, m, 64);
    if (lane == 0) red[w] = toe;
    __syncthreads();
    if (t == 0) {
        float tt = red[0] + red[1] + red[2] + red[3]
                 + red[4] + red[5] + red[6] + red[7];
        atomicAdd(&acc[2], tt);
    }
}

__global__ __launch_bounds__(512) void k_fin(
        const float* __restrict__ colTot, const float* __restrict__ acc,
        float* __restrict__ out) {
    __shared__ float red[8];
    const int t = threadIdx.x, lane = t & 63, w = t >> 6;
    float p   = fmaxf(colTot[t] * (1.f / B_ROWS), EPS);
    float ent = -p * __logf(p);
#pragma unroll
    for (int m = 32; m >= 1; m >>= 1) ent += __shfl_xor(ent, m, 64);
    if (lane == 0) red[w] = ent;
    __syncthreads();
    if (t == 0) {
        float entropy = red[0] + red[1] + red[2] + red[3]
                      + red[4] + red[5] + red[6] + red[7];
        float consistency = -acc[0] * (1.f / B_ROWS);
        float second      = acc[1] * EPS;
        float third       = acc[2] * EPS * (1.f / N_COLS);
        float third_weight = 0.5f / sqrtf((float)N_COLS);
        float diff_weight  = 0.25f / (float)N_COLS;
        out[0] = consistency - 2.0f * entropy + diff_weight * second
                 - third_weight * third;
        out[1] = consistency;
        out[2] = entropy;
        out[3] = second;
        out[4] = third;
    }
}

extern "C" void kernel_launch(void* const* d_in, const int* in_sizes, int n_in,
                              void* d_out, int out_size, void* d_ws, size_t ws_size,
                              hipStream_t stream) {
    const float* anchors   = (const float*)d_in[0];
    const float* neighbors = (const float*)d_in[1];
    float* out = (float*)d_out;

    float* sim    = (float*)d_ws;            // 65536 f32
    float* colsum = sim + B_ROWS;            // 128*512 f32 (256 KB)
    float* colTot = colsum + 128 * 512;      // 512 f32
    float* acc    = colTot + 512;            // 16 f32

    // zero colsum + colTot + acc (sim is fully overwritten by k_main)
    hipMemsetAsync(colsum, 0, (128 * 512 + 512 + 16) * sizeof(float), stream);

    k_main<<<dim3(GRID1), dim3(256), 0, stream>>>(
        anchors, neighbors, sim, colsum, acc);
    k_red<<<dim3(64), dim3(512), 0, stream>>>(colsum, sim, colTot, acc);
    k_fin<<<dim3(1), dim3(512), 0, stream>>>(colTot, acc, out);
}